// Round 2
// baseline (349.194 us; speedup 1.0000x reference)
//
#include <hip/hip_runtime.h>
#include <hip/hip_bf16.h>

#define BB 64
#define TT 1024
#define DD 512
#define NS 24

#define POT_OFF   65536
#define LENS_OFF  1638400
#define TRANS_OFF 1638464

// ---------------------------------------------------------------------------
// Kernel 1: pot = x @ W + b (+ boundary adds).  (unchanged this round)
// ---------------------------------------------------------------------------
__global__ __launch_bounds__(256) void gemm_pot(
    const float* __restrict__ x, const float* __restrict__ W,
    const float* __restrict__ bias, const float* __restrict__ trans,
    const float* __restrict__ lb, const float* __restrict__ rb,
    float* __restrict__ out)
{
  __shared__ float wl[DD * NS];              // 49,152 B: W, then partials
  const int tid = threadIdx.x;
  const int l   = tid & 63;
  const int q   = tid >> 6;                  // K-quarter
  const int row = blockIdx.x * 64 + l;

  // stage W: 12288 floats = 256 threads x 12 float4, coalesced
  {
    const float4* Ws = (const float4*)W;
    float4* Wd = (float4*)wl;
#pragma unroll
    for (int i = 0; i < 12; ++i) Wd[tid + i * 256] = Ws[tid + i * 256];
  }
  __syncthreads();

  const float4* xp = (const float4*)(x + (size_t)row * DD + q * 128);

  float acc[NS];
#pragma unroll
  for (int nn = 0; nn < NS; ++nn) acc[nn] = 0.f;

  float4 buf[8];
#pragma unroll
  for (int i = 0; i < 8; ++i) buf[i] = xp[i];

#pragma unroll
  for (int f = 0; f < 32; ++f) {             // 32 float4 = 128 k per quarter
    float4 v = buf[f & 7];
    if (f + 8 < 32) buf[f & 7] = xp[f + 8];  // refill window
    const float xj[4] = {v.x, v.y, v.z, v.w};
#pragma unroll
    for (int j = 0; j < 4; ++j) {
      const int k = q * 128 + f * 4 + j;
      const float4* wr = (const float4*)&wl[k * NS];   // same addr all lanes
      float4 w0 = wr[0], w1 = wr[1], w2 = wr[2], w3 = wr[3], w4 = wr[4], w5 = wr[5];
      const float wv[NS] = {w0.x,w0.y,w0.z,w0.w, w1.x,w1.y,w1.z,w1.w,
                            w2.x,w2.y,w2.z,w2.w, w3.x,w3.y,w3.z,w3.w,
                            w4.x,w4.y,w4.z,w4.w, w5.x,w5.y,w5.z,w5.w};
      const float xv = xj[j];
#pragma unroll
      for (int nn = 0; nn < NS; ++nn) acc[nn] = fmaf(xv, wv[nn], acc[nn]);
    }
  }

  // reduce the 4 K-quarter partials through W's (now dead) LDS region
  __syncthreads();
  if (q != 0) {
#pragma unroll
    for (int nn = 0; nn < NS; ++nn) wl[((q - 1) * 64 + l) * 25 + nn] = acc[nn];
  }
  __syncthreads();
  if (q == 0) {
    const int t = row & (TT - 1);
#pragma unroll
    for (int nn = 0; nn < NS; ++nn)
      acc[nn] += wl[(0 * 64 + l) * 25 + nn] + wl[(1 * 64 + l) * 25 + nn]
               + wl[(2 * 64 + l) * 25 + nn] + bias[nn];
    if (t == 0) {
#pragma unroll
      for (int nn = 0; nn < NS; ++nn) acc[nn] += lb[nn];
    }
    if (t == TT - 1) {
#pragma unroll
      for (int nn = 0; nn < NS; ++nn) acc[nn] += rb[nn];
    }
    float* po = out + POT_OFF + (size_t)row * NS;
#pragma unroll
    for (int i = 0; i < 6; ++i)
      *(float4*)(po + i * 4) = make_float4(acc[4*i], acc[4*i+1], acc[4*i+2], acc[4*i+3]);
  }

  if (blockIdx.x == 0 && tid < BB) out[LENS_OFF + tid] = (float)TT;
  if (blockIdx.x == 1) {
    for (int i = tid; i < NS * NS; i += 256) out[TRANS_OFF + i] = trans[i];
  }
}

__device__ __forceinline__ float m3(float a, float b, float c) {
  return fmaxf(fmaxf(a, b), c);   // clang fuses to v_max3_f32
}

// ---------------------------------------------------------------------------
// Kernel 2 (fused): scan + bp + backtrace, one block per batch, 1024 threads.
// Scan: alpha held WAVE-UNIFORM in 24 SGPRs (v_readlane after each step).
// Lane n (0..23; 24..63 duplicate n=23) does the FULL 24-way max-plus reduce
// for its column: 24 v_add_f32 (SGPR+VGPR) + 12 v_max3 + 1 add.
// Alpha is ds_write'n for the bp-build but NEVER read back during the scan —
// zero DS ops on the serial dependency chain (previous version had
// bpermute + write + 3x b128 readback ~250 cy/step of DS latency).
// ---------------------------------------------------------------------------
__global__ __launch_bounds__(1024) void viterbi_fused(
    const float* __restrict__ pot, const float* __restrict__ trans,
    float* __restrict__ out_dec)
{
  __shared__ float ps[(TT + 8) * NS];     // pot rows, overwritten by alpha
  __shared__ unsigned char bl[TT * NS];   // backpointers
  __shared__ float tl[NS * NS];           // trans
  __shared__ int H[32][NS];
  __shared__ int e[32];

  const int b = blockIdx.x, tid = threadIdx.x;

  // ---- stage pot[b] + trans ----
  {
    const float4* src = (const float4*)(pot + (size_t)b * TT * NS);
    float4* dst = (float4*)ps;
#pragma unroll
    for (int i = 0; i < 6; ++i) dst[tid + i * 1024] = src[tid + i * 1024];
    if (tid < NS * NS) tl[tid] = trans[tid];
  }
  __syncthreads();

  // ---- forward scan: wave 0 only, alpha in SGPRs ----
  if (tid < 64) {
    const int n = (tid < 24) ? tid : 23;   // lanes 24..63 duplicate n=23

    float tc[NS];                          // trans column n, per-lane regs
#pragma unroll
    for (int m = 0; m < NS; ++m) tc[m] = tl[m * NS + n];

    // init alpha = pot row 0: lane n holds alpha0[n], broadcast to SGPRs
    float a_own = ps[n];
    float sal[NS];
#pragma unroll
    for (int m = 0; m < NS; ++m)
      sal[m] = __int_as_float(__builtin_amdgcn_readlane(__float_as_int(a_own), m));

    float pv[8];                           // pot prefetch ring (off-chain)
#pragma unroll
    for (int u = 0; u < 8; ++u) pv[u] = ps[(1 + u) * NS + n];

    auto step = [&](int tt, float potv) {
      float sc[NS];
#pragma unroll
      for (int m = 0; m < NS; ++m) sc[m] = sal[m] + tc[m];
      float v0 = m3(sc[0],  sc[1],  sc[2]);
      float v1 = m3(sc[3],  sc[4],  sc[5]);
      float v2 = m3(sc[6],  sc[7],  sc[8]);
      float v3 = m3(sc[9],  sc[10], sc[11]);
      float v4 = m3(sc[12], sc[13], sc[14]);
      float v5 = m3(sc[15], sc[16], sc[17]);
      float v6 = m3(sc[18], sc[19], sc[20]);
      float v7 = m3(sc[21], sc[22], sc[23]);
      float w0 = m3(v0, v1, v2);
      float w1 = m3(v3, v4, v5);
      float w2 = fmaxf(v6, v7);
      float pm = m3(w0, w1, w2);
      float anew = pm + potv;              // exact: single add, max exact
      ps[tt * NS + n] = anew;              // fire-and-forget (bp-build later)
#pragma unroll
      for (int m = 0; m < NS; ++m)
        sal[m] = __int_as_float(__builtin_amdgcn_readlane(__float_as_int(anew), m));
    };

    for (int t = 1; t + 7 <= TT - 1; t += 8) {
#pragma unroll
      for (int u = 0; u < 8; ++u) {
        const int tt = t + u;
        const float potv = pv[u];
        pv[u] = ps[(tt + 8) * NS + n];     // 8 ahead of overwrite frontier
        step(tt, potv);
      }
    }
#pragma unroll
    for (int u = 0; u < 7; ++u) step(1017 + u, pv[u]);
  }
  __syncthreads();

  // ---- bp build from LDS alphas (bit-exact, first-max strict >) ----
  for (int idx = tid; idx < (TT - 1) * NS; idx += 1024) {
    const int n = idx % NS;
    const int t = idx / NS + 1;
    const float* ar = &ps[(t - 1) * NS];
    float best = ar[0] + tl[n];
    int bi = 0;
#pragma unroll
    for (int m = 1; m < NS; ++m) {
      float s = ar[m] + tl[m * NS + n];
      bool g = s > best;
      bi = g ? m : bi;
      best = g ? s : best;
    }
    bl[t * NS + n] = (unsigned char)bi;
  }
  __syncthreads();

  // ---- backtrace: chunk composition (C=32) ----
  if (tid < 32 * NS) {
    const int c = tid / NS, s = tid % NS;
    int a = s;
    int tlo = c * 32; if (tlo < 1) tlo = 1;
    for (int t = c * 32 + 31; t >= tlo; --t) a = bl[t * NS + a];
    H[c][s] = a;
  }
  __syncthreads();

  if (tid == 0) {
    const float* ar = &ps[(TT - 1) * NS];
    float best = ar[0]; int bi = 0;
#pragma unroll
    for (int nn = 1; nn < NS; ++nn) {
      float v = ar[nn];
      if (v > best) { best = v; bi = nn; }
    }
    int tag = bi;
    e[31] = tag;
    for (int c = 31; c >= 1; --c) { tag = H[c][tag]; e[c - 1] = tag; }
  }
  __syncthreads();

  if (tid < 32) {
    const int c = tid;
    int tag = e[c];
    float* od = out_dec + (size_t)b * TT;
    od[c * 32 + 31] = (float)tag;
    for (int t = c * 32 + 30; t >= c * 32; --t) {
      tag = bl[(t + 1) * NS + tag];
      od[t] = (float)tag;
    }
  }
}

// ---------------------------------------------------------------------------
extern "C" void kernel_launch(void* const* d_in, const int* in_sizes, int n_in,
                              void* d_out, int out_size, void* d_ws, size_t ws_size,
                              hipStream_t stream)
{
  const float* x     = (const float*)d_in[0];
  const float* W     = (const float*)d_in[1];
  const float* bias  = (const float*)d_in[2];
  const float* trans = (const float*)d_in[3];
  const float* lb    = (const float*)d_in[4];
  const float* rb    = (const float*)d_in[5];
  float* out = (float*)d_out;

  gemm_pot<<<1024, 256, 0, stream>>>(x, W, bias, trans, lb, rb, out);
  viterbi_fused<<<BB, 1024, 0, stream>>>(out + POT_OFF, trans, out);
}